// Round 16
// baseline (52.087 us; speedup 1.0000x reference)
//
#include <hip/hip_runtime.h>
#include <hip/hip_bf16.h>
#include <stdint.h>
#include <stddef.h>

// Problem constants
#define B_    2
#define NREF  3
#define FDIM  256
#define HW    4096
#define DCLS  10
#define RTOT  12288          // NREF*HW reference pixels per batch
#define TT    128            // target pixels per block (8 waves of 32r x 32t)
#define RR    64             // reference pixels per chunk
#define RS    8              // r-axis split across blocks
#define RPB   1536           // RTOT/RS
#define NCH   24             // RPB/RR
#define NPIX  8192           // B_*HW
#define LOG2E 1.44269504f
#define C0f   (-144.269504f)   // -100*LOG2E
#define SAQ   21.1666667f      // i8 quant scale = 127/6 (inputs ~N(0,1), clip 6 sigma)
// sim = acc/SAQ^2 ; P = exp(sim-100) = exp2(acc*SC2 + C0f)
#define SC2   (LOG2E / (SAQ * SAQ))

typedef __attribute__((ext_vector_type(8))) short bf16x8;
typedef __attribute__((ext_vector_type(4))) float f32x4;
typedef __attribute__((ext_vector_type(4))) int i32x4;
typedef __attribute__((ext_vector_type(4))) unsigned int u32x4;

__device__ __forceinline__ unsigned short f2bf(float x) {
  union { float f; unsigned u; } v; v.f = x;
  unsigned r = v.u + 0x7fffu + ((v.u >> 16) & 1u);   // RNE
  return (unsigned short)(r >> 16);
}
// single-instruction packed f32->bf16 (RNE), gfx950
__device__ __forceinline__ unsigned cvtpk(float a, float b) {
  unsigned r;
  asm("v_cvt_pk_bf16_f32 %0, %1, %2" : "=v"(r) : "v"(a), "v"(b));
  return r;
}
// async global->LDS, 16B per lane; LDS dest is wave-uniform base + lane*16
__device__ __forceinline__ void async16(const void* g, void* l) {
  __builtin_amdgcn_global_load_lds(
      (const __attribute__((address_space(1))) void*)g,
      (__attribute__((address_space(3))) void*)l, 16, 0, 0);
}
// one-hot pair: low/high 16-bit bf16 1.0 where label byte matches d
__device__ __forceinline__ unsigned oh2(unsigned word, int d) {
  return ((word & 255u) == (unsigned)d ? 0x3F80u : 0u) |
         (((word >> 8) & 255u) == (unsigned)d ? 0x3F800000u : 0u);
}
// quantize one float to i8 (already scaled), return low byte
__device__ __forceinline__ int q8(float v) {
  v = fminf(fmaxf(v, -127.f), 127.f);
  return (int)rintf(v);
}

// ---------------- kernel 1: fused prep (transpose+quantize i8) + label extract ----------------
// blocks [0,1024): ref/tgt -> i8 rows of 256B with XOR swizzle baked per row.
// Each block: 32 rows x 8 threads/row x 2 chunks of 16 elems -> FULL 16-chunk coverage.
// blocks [1024,1120): one-hot -> u8 labels.
__global__ __launch_bounds__(256) void k_pre(const float* __restrict__ ref,
                                             const float* __restrict__ tgt,
                                             const float* __restrict__ rl,
                                             char* __restrict__ outb,
                                             unsigned char* __restrict__ lab8) {
  const int tid = threadIdx.x;
  if (blockIdx.x < 1024) {
    const int row = blockIdx.x * 32 + (tid & 31);     // row 0..32767 (lane-coalesced)
    const int q = tid >> 5;                           // eighth 0..7
    const float* src;
    if (row < B_ * RTOT) {
      const int b = row / RTOT, rr2 = row % RTOT;
      src = ref + ((size_t)(b * NREF + (rr2 >> 12)) * FDIM) * HW + (rr2 & 4095);
    } else {
      const int r2 = row - B_ * RTOT;
      src = tgt + ((size_t)(r2 >> 12) * FDIM) * HW + (r2 & 4095);
    }
    char* dst = outb + (size_t)row * 256;
    const int sw = (row & 7) << 4;
#pragma unroll
    for (int ci = 0; ci < 2; ++ci) {
      const int c16 = q * 2 + ci;                     // 16-byte chunk 0..15 (FULL row)
      int qv[16];
#pragma unroll
      for (int j = 0; j < 16; ++j)
        qv[j] = q8(src[(size_t)(c16 * 16 + j) * HW] * SAQ);
      u32x4 u;
#pragma unroll
      for (int g = 0; g < 4; ++g)
        u[g] = (unsigned)(qv[g * 4] & 255) | ((unsigned)(qv[g * 4 + 1] & 255) << 8) |
               ((unsigned)(qv[g * 4 + 2] & 255) << 16) | ((unsigned)(qv[g * 4 + 3] & 255) << 24);
      *(u32x4*)(dst + ((c16 * 16) ^ sw)) = u;
    }
  } else {
    const int idx = (blockIdx.x - 1024) * 256 + tid;   // < 24576
    if (idx >= B_ * RTOT) return;
    const int b = idx / RTOT, r = idx % RTOT;
    const float* p = rl + ((size_t)((b * NREF + (r >> 12)) * DCLS)) * HW + (r & 4095);
    int v = 0;
#pragma unroll
    for (int d = 1; d < DCLS; ++d)
      if (p[(size_t)d * HW] > 0.5f) v = d;
    lab8[idx] = (unsigned char)v;
  }
}

// ---------------- kernel 2: fused QK(i8)-softmax-PV(bf16), 8-wave blocks ----------------
// grid = RS(8) * 32(tblocks) * B_(2) = 512 blocks of 512 threads (8 waves).
// Wave tile 32r x 32t: rh = w>>2 (r-half of the 64-r chunk), th = w&3 (t-quarter).
// i8 halves bfr to 32 VGPR and acc to 16 -> total ~90 VGPR fits the <=128 tier:
// __launch_bounds__(512,4) -> 2 blocks/CU x 8 waves = 16 waves/CU = 4 waves/SIMD,
// DOUBLE the latency hiding of the r8-r15 2-wave/SIMD structure. Per-chunk
// QK/pv logic identical to verified r15 (nt 4 -> 2).
__global__ __launch_bounds__(512, 4) void k_main(const char* __restrict__ refb,
                                                 const char* __restrict__ tgtb,
                                                 const unsigned char* __restrict__ lab8,
                                                 float* __restrict__ pred) {
  __shared__ __align__(16) char Ash[2][RR * 256];   // double-buffered i8 chunk, 32 KB

  const int tid = threadIdx.x;
  const int lane = tid & 63;
  const int w = tid >> 6;                // wave 0..7
  const int l15 = lane & 15, l4 = lane >> 4;
  const int rh = w >> 2, th = w & 3;     // wave sub-tile: 32r x 32t
  const int swz = (l15 & 7) << 4;

  const int bid = blockIdx.x;
  const int rs = bid & 7;
  const int tb = (bid >> 3) & 31;
  const int b  = bid >> 8;

  // ---- B fragments in registers: wave's 32 t x full K=256 i8 (32 VGPR) ----
  i32x4 bfr[2][4];
  {
    const char* base = tgtb + ((size_t)(b * HW + tb * TT + th * 32)) * 256;
#pragma unroll
    for (int nt = 0; nt < 2; ++nt) {
      const char* rp = base + (size_t)((nt * 16 + l15) * 256);
#pragma unroll
      for (int ks = 0; ks < 4; ++ks)
        bfr[nt][ks] = *(const i32x4*)(rp + ((ks * 64 + l4 * 16) ^ swz));
    }
  }

  f32x4 pacc[2];
  pacc[0] = f32x4{0.f, 0.f, 0.f, 0.f};
  pacc[1] = f32x4{0.f, 0.f, 0.f, 0.f};

  const char* Asrc = refb + ((size_t)(b * RTOT + rs * RPB)) * 256;

  // precomputed A-read base pointers (buf0); buf1 reached via +16384 immediate
  const char* ap00 = &Ash[0][(rh * 32 +  0 + l15) * 256 + ((     l4 * 16) ^ swz)];
  const char* ap01 = &Ash[0][(rh * 32 +  0 + l15) * 256 + ((64 + l4 * 16) ^ swz)];
  const char* ap10 = &Ash[0][(rh * 32 + 16 + l15) * 256 + ((     l4 * 16) ^ swz)];
  const char* ap11 = &Ash[0][(rh * 32 + 16 + l15) * 256 + ((64 + l4 * 16) ^ swz)];

  // stage chunk at src -> dbuf (16 KB = 16 segs of 1 KB, 2 per wave)
  auto stage = [&](const char* s, char* dbuf) {
#pragma unroll
    for (int i2 = 0; i2 < 2; ++i2) {
      const int seg = i2 * 8 + w;
      async16(s + seg * 1024 + lane * 16, dbuf + seg * 1024);
    }
  };
  // QK^T of one chunk: 16 i8-MFMA/wave (K=64 each); int accumulate (exact)
  auto qk = [&](i32x4 (&acc)[2][2], const int OFS) {
#pragma unroll
    for (int i2 = 0; i2 < 2; ++i2)
#pragma unroll
      for (int j = 0; j < 2; ++j) acc[i2][j] = i32x4{0, 0, 0, 0};
    __builtin_amdgcn_s_setprio(1);
#pragma unroll
    for (int ks = 0; ks < 4; ++ks) {
      const int ko = OFS + (ks >> 1) * 128;
      const i32x4 af0 = *(const i32x4*)(((ks & 1) ? ap01 : ap00) + ko);
      const i32x4 af1 = *(const i32x4*)(((ks & 1) ? ap11 : ap10) + ko);
#pragma unroll
      for (int nt = 0; nt < 2; ++nt)
        acc[0][nt] = __builtin_amdgcn_mfma_i32_16x16x64_i8(
            af0, bfr[nt][ks], acc[0][nt], 0, 0, 0);
#pragma unroll
      for (int nt = 0; nt < 2; ++nt)
        acc[1][nt] = __builtin_amdgcn_mfma_i32_16x16x64_i8(
            af1, bfr[nt][ks], acc[1][nt], 0, 0, 0);
    }
    __builtin_amdgcn_s_setprio(0);
  };
  // dequant+exp2+pack+PV (wave-local; C/D reg layout IS the PV B-frag layout)
  auto pv = [&](const i32x4 (&acc)[2][2], unsigned la, unsigned lb2) {
    union { bf16x8 v; unsigned u[4]; } lf;
    lf.u[0] = oh2(la, l15);        lf.u[1] = oh2(la >> 16, l15);
    lf.u[2] = oh2(lb2, l15);       lf.u[3] = oh2(lb2 >> 16, l15);
#pragma unroll
    for (int nt = 0; nt < 2; ++nt) {
      const i32x4 a0 = acc[0][nt], a1 = acc[1][nt];
      float p0 = __builtin_amdgcn_exp2f(__builtin_fmaf((float)a0[0], SC2, C0f));
      float p1 = __builtin_amdgcn_exp2f(__builtin_fmaf((float)a0[1], SC2, C0f));
      float p2 = __builtin_amdgcn_exp2f(__builtin_fmaf((float)a0[2], SC2, C0f));
      float p3 = __builtin_amdgcn_exp2f(__builtin_fmaf((float)a0[3], SC2, C0f));
      float p4 = __builtin_amdgcn_exp2f(__builtin_fmaf((float)a1[0], SC2, C0f));
      float p5 = __builtin_amdgcn_exp2f(__builtin_fmaf((float)a1[1], SC2, C0f));
      float p6 = __builtin_amdgcn_exp2f(__builtin_fmaf((float)a1[2], SC2, C0f));
      float p7 = __builtin_amdgcn_exp2f(__builtin_fmaf((float)a1[3], SC2, C0f));
      union { bf16x8 v; unsigned u[4]; } pf;
      pf.u[0] = cvtpk(p0, p1); pf.u[1] = cvtpk(p2, p3);
      pf.u[2] = cvtpk(p4, p5); pf.u[3] = cvtpk(p6, p7);
      pacc[nt] = __builtin_amdgcn_mfma_f32_16x16x32_bf16(lf.v, pf.v, pacc[nt], 0, 0, 0);
    }
  };

  i32x4 acc[2][2];
  const unsigned char* lbp = lab8 + b * RTOT + rs * RPB + rh * 32 + l4 * 4;
  const char* Acur = Asrc + 2 * (RR * 256);   // global source of chunk 2

  // prologue: labels(0); stage(0)->buf0; drain; stage(1)->buf1; qk(0)
  unsigned la_p = *(const unsigned*)lbp;
  unsigned lb_p = *(const unsigned*)(lbp + 16);
  lbp += RR;
  stage(Asrc, &Ash[0][0]);
  __syncthreads();
  stage(Asrc + RR * 256, &Ash[1][0]);
  qk(acc, 0);

#pragma unroll 1
  for (int i = 0; i < 11; ++i) {
    {   // step: chunk c=1+2i (odd, buf1); labels(c) loaded AFTER barrier
      __syncthreads();                   // all pending vmem >= 1 chunk old
      const unsigned la_n = *(const unsigned*)lbp;
      const unsigned lb_n = *(const unsigned*)(lbp + 16);
      lbp += RR;
      stage(Acur, &Ash[0][0]); Acur += RR * 256;
      pv(acc, la_p, lb_p);               // chunk c-1 (regs only)
      qk(acc, 16384);                    // chunk c from buf1
      la_p = la_n; lb_p = lb_n;
    }
    {   // step: chunk c=2+2i (even, buf0)
      __syncthreads();
      const unsigned la_n = *(const unsigned*)lbp;
      const unsigned lb_n = *(const unsigned*)(lbp + 16);
      lbp += RR;
      stage(Acur, &Ash[1][0]); Acur += RR * 256;
      pv(acc, la_p, lb_p);               // chunk c-1
      qk(acc, 0);                        // chunk c from buf0
      la_p = la_n; lb_p = lb_n;
    }
  }
  {   // chunk 23 (odd, buf1): no stage; then final pv(23)
    __syncthreads();                     // drain DMA(23) (1 chunk old)
    const unsigned la_n = *(const unsigned*)lbp;   // labels(23)
    const unsigned lb_n = *(const unsigned*)(lbp + 16);
    pv(acc, la_p, lb_p);                 // chunk 22
    qk(acc, 16384);                      // chunk 23
    pv(acc, la_n, lb_n);                 // chunk 23
  }

  // ---- cross-wave reduction of rh pairs (once), then global write ----
  __syncthreads();                       // everyone done with Ash (no DMA pending)
  float* sc = (float*)&Ash[0][0];        // 8 KB scratch
  if (rh == 1) {
#pragma unroll
    for (int nt = 0; nt < 2; ++nt)
      *(f32x4*)&sc[((th * 64 + lane) * 2 + nt) * 4] = pacc[nt];
  }
  __syncthreads();
  if (rh == 0) {
#pragma unroll
    for (int nt = 0; nt < 2; ++nt) {
      pacc[nt] += *(const f32x4*)&sc[((th * 64 + lane) * 2 + nt) * 4];
      const int t = tb * TT + th * 32 + nt * 16 + l15;
      const size_t o = (((size_t)(rs * B_ + b)) * HW + t) * 16 + l4 * 4;
      *(f32x4*)&pred[o] = pacc[nt];
    }
  }
}

// ---------------- kernel 3: per-pixel loss terms + block reduce ----------------
__global__ __launch_bounds__(256) void k_epi(const float* __restrict__ pred,
                                             const int* __restrict__ tl,
                                             float* __restrict__ red) {
  const int idx = blockIdx.x * 256 + threadIdx.x;   // < 8192
  const int b = idx >> 12, t = idx & 4095;
  union { f32x4 v[3]; float f[12]; } S;
  S.v[0] = f32x4{0.f, 0.f, 0.f, 0.f};
  S.v[1] = f32x4{0.f, 0.f, 0.f, 0.f};
  S.v[2] = f32x4{0.f, 0.f, 0.f, 0.f};
#pragma unroll
  for (int r = 0; r < RS; ++r) {
    const f32x4* p = (const f32x4*)&pred[(((size_t)(r * B_ + b)) * HW + t) * 16];
    S.v[0] += p[0]; S.v[1] += p[1]; S.v[2] += p[2];
  }
  float T = 0.f;
#pragma unroll
  for (int d = 0; d < DCLS; ++d) T += S.f[d];
  const float inv = 1.f / T;
  const int lb = tl[idx];
  float se = 0.f, zt = 0.f;
#pragma unroll
  for (int d = 0; d < DCLS; ++d) {
    const float z = S.f[d] * inv;      // pred prob in [0,1]
    se += __expf(z);
    if (d == lb) zt = z;
  }
  const float logpt = zt - __logf(se);
  const float pt = __expf(zt) / se;
  const float focal = sqrtf(fmaxf(1.f - pt, 0.f));   // gamma = 0.5

  float lp = logpt, fo = focal;
#pragma unroll
  for (int off = 32; off; off >>= 1) {
    lp += __shfl_down(lp, off);
    fo += __shfl_down(fo, off);
  }
  __shared__ float rb_[8];
  const int lane = threadIdx.x & 63, wv = threadIdx.x >> 6;
  if (lane == 0) { rb_[wv] = lp; rb_[4 + wv] = fo; }
  __syncthreads();
  if (threadIdx.x == 0) {
    red[blockIdx.x * 2 + 0] = rb_[0] + rb_[1] + rb_[2] + rb_[3];
    red[blockIdx.x * 2 + 1] = rb_[4] + rb_[5] + rb_[6] + rb_[7];
  }
}

// ---------------- kernel 4: final scalar ----------------
__global__ void k_fin(const float* __restrict__ red, float* __restrict__ out) {
  const int tid = threadIdx.x;   // 64
  float lp = 0.f, fo = 0.f;
  if (tid < 32) { lp = red[tid * 2]; fo = red[tid * 2 + 1]; }
#pragma unroll
  for (int off = 16; off; off >>= 1) {
    lp += __shfl_down(lp, off);
    fo += __shfl_down(fo, off);
  }
  if (tid == 0) {
    const float ce = -lp / (float)NPIX;       // ce = -mean(log_pt)
    out[0] = ce * (fo / (float)NPIX);         // loss = ce * mean(focal)
  }
}

extern "C" void kernel_launch(void* const* d_in, const int* in_sizes, int n_in,
                              void* d_out, int out_size, void* d_ws, size_t ws_size,
                              hipStream_t stream)
{
  const float* ref  = (const float*)d_in[0];
  const float* tgt  = (const float*)d_in[1];
  const float* rl   = (const float*)d_in[2];
  const int*   tlab = (const int*)d_in[3];
  float* out = (float*)d_out;

  char* ws = (char*)d_ws;
  char* refb = ws;                                    // 32768 rows * 256 B = 8 MB (ref + tgt)
  char* tgtb = ws + (size_t)24576 * 256;              // tgt rows start at 24576
  unsigned char* lab8 = (unsigned char*)(ws + 8388608);           // 24 KB (pad 32 KB)
  float* pred = (float*)(ws + 8388608 + 32768);                   // 4 MB (RS*B*HW*16 f32)
  float* red  = (float*)(ws + 8388608 + 32768 + 4194304);         // 256 B

  k_pre<<<1120, 256, 0, stream>>>(ref, tgt, rl, refb, lab8);
  k_main<<<512, 512, 0, stream>>>(refb, tgtb, lab8, pred);
  k_epi<<<32, 256, 0, stream>>>(pred, tlab, red);
  k_fin<<<1, 64, 0, stream>>>(red, out);
}

// Round 17
// 51.339 us; speedup vs baseline: 1.0146x; 1.0146x over previous
//
#include <hip/hip_runtime.h>
#include <hip/hip_bf16.h>
#include <stdint.h>
#include <stddef.h>

// Problem constants
#define B_    2
#define NREF  3
#define FDIM  256
#define HW    4096
#define DCLS  10
#define RTOT  12288          // NREF*HW reference pixels per batch
#define TT    128            // target pixels per block (8 waves of 32r x 32t)
#define RR    64             // reference pixels per chunk
#define RS    8              // r-axis split across blocks
#define RPB   1536           // RTOT/RS
#define NCH   24             // RPB/RR
#define NPIX  8192           // B_*HW
#define LOG2E 1.44269504f
#define C0f   (-144.269504f)   // -100*LOG2E
#define SAQ   21.1666667f      // i8 quant scale = 127/6 (inputs ~N(0,1), clip 6 sigma)
// sim = acc/SAQ^2 ; P = exp(sim-100) = exp2(acc*SC2 + C0f)
#define SC2   (LOG2E / (SAQ * SAQ))

typedef __attribute__((ext_vector_type(8))) short bf16x8;
typedef __attribute__((ext_vector_type(4))) float f32x4;
typedef __attribute__((ext_vector_type(4))) int i32x4;
typedef __attribute__((ext_vector_type(4))) unsigned int u32x4;

__device__ __forceinline__ unsigned short f2bf(float x) {
  union { float f; unsigned u; } v; v.f = x;
  unsigned r = v.u + 0x7fffu + ((v.u >> 16) & 1u);   // RNE
  return (unsigned short)(r >> 16);
}
// single-instruction packed f32->bf16 (RNE), gfx950
__device__ __forceinline__ unsigned cvtpk(float a, float b) {
  unsigned r;
  asm("v_cvt_pk_bf16_f32 %0, %1, %2" : "=v"(r) : "v"(a), "v"(b));
  return r;
}
// async global->LDS, 16B per lane; LDS dest is wave-uniform base + lane*16
__device__ __forceinline__ void async16(const void* g, void* l) {
  __builtin_amdgcn_global_load_lds(
      (const __attribute__((address_space(1))) void*)g,
      (__attribute__((address_space(3))) void*)l, 16, 0, 0);
}
// one-hot pair: low/high 16-bit bf16 1.0 where label byte matches d
__device__ __forceinline__ unsigned oh2(unsigned word, int d) {
  return ((word & 255u) == (unsigned)d ? 0x3F80u : 0u) |
         (((word >> 8) & 255u) == (unsigned)d ? 0x3F800000u : 0u);
}
// quantize one float to i8 (already scaled), return low byte
__device__ __forceinline__ int q8(float v) {
  v = fminf(fmaxf(v, -127.f), 127.f);
  return (int)rintf(v);
}

// ---------------- kernel 1: fused prep (transpose+quantize i8) + label extract ----------------
// blocks [0,1024): ref/tgt -> i8 rows of 256B with XOR swizzle baked per row.
// Each block: 32 rows x 8 threads/row x 2 chunks of 16 elems -> FULL 16-chunk coverage.
// blocks [1024,1120): one-hot -> u8 labels.
__global__ __launch_bounds__(256) void k_pre(const float* __restrict__ ref,
                                             const float* __restrict__ tgt,
                                             const float* __restrict__ rl,
                                             char* __restrict__ outb,
                                             unsigned char* __restrict__ lab8) {
  const int tid = threadIdx.x;
  if (blockIdx.x < 1024) {
    const int row = blockIdx.x * 32 + (tid & 31);     // row 0..32767 (lane-coalesced)
    const int q = tid >> 5;                           // eighth 0..7
    const float* src;
    if (row < B_ * RTOT) {
      const int b = row / RTOT, rr2 = row % RTOT;
      src = ref + ((size_t)(b * NREF + (rr2 >> 12)) * FDIM) * HW + (rr2 & 4095);
    } else {
      const int r2 = row - B_ * RTOT;
      src = tgt + ((size_t)(r2 >> 12) * FDIM) * HW + (r2 & 4095);
    }
    char* dst = outb + (size_t)row * 256;
    const int sw = (row & 7) << 4;
#pragma unroll
    for (int ci = 0; ci < 2; ++ci) {
      const int c16 = q * 2 + ci;                     // 16-byte chunk 0..15 (FULL row)
      int qv[16];
#pragma unroll
      for (int j = 0; j < 16; ++j)
        qv[j] = q8(src[(size_t)(c16 * 16 + j) * HW] * SAQ);
      u32x4 u;
#pragma unroll
      for (int g = 0; g < 4; ++g)
        u[g] = (unsigned)(qv[g * 4] & 255) | ((unsigned)(qv[g * 4 + 1] & 255) << 8) |
               ((unsigned)(qv[g * 4 + 2] & 255) << 16) | ((unsigned)(qv[g * 4 + 3] & 255) << 24);
      *(u32x4*)(dst + ((c16 * 16) ^ sw)) = u;
    }
  } else {
    const int idx = (blockIdx.x - 1024) * 256 + tid;   // < 24576
    if (idx >= B_ * RTOT) return;
    const int b = idx / RTOT, r = idx % RTOT;
    const float* p = rl + ((size_t)((b * NREF + (r >> 12)) * DCLS)) * HW + (r & 4095);
    int v = 0;
#pragma unroll
    for (int d = 1; d < DCLS; ++d)
      if (p[(size_t)d * HW] > 0.5f) v = d;
    lab8[idx] = (unsigned char)v;
  }
}

// ---------------- kernel 2: fused QK(i8)-softmax-PV(bf16), wave-parity staggered ----------------
// grid = RS(8) * 32(tblocks) * B_(2) = 512 blocks of 512 threads (8 waves), 2 blocks/CU.
// ANTI-PHASE: after each barrier, EVEN waves run pv(prev)->qk(cur) (VALU burst first),
// ODD waves run qk(cur)->pv(prev) (MFMA burst first). Half the waves on each SIMD
// feed the matrix pipe while the other half feed the VALU pipe (m114 co-execution),
// breaking the barrier-lockstep phase alignment that r10/r16 showed occupancy can't
// fix. Odd path forces genuine dual accumulators (accE live across qk(accO)) — in i8
// that is only +16 VGPR (~110 total, stays in the <=128 tier, 4 waves/SIMD).
__global__ __launch_bounds__(512, 4) void k_main(const char* __restrict__ refb,
                                                 const char* __restrict__ tgtb,
                                                 const unsigned char* __restrict__ lab8,
                                                 float* __restrict__ pred) {
  __shared__ __align__(16) char Ash[2][RR * 256];   // double-buffered i8 chunk, 32 KB

  const int tid = threadIdx.x;
  const int lane = tid & 63;
  const int w = tid >> 6;                // wave 0..7
  const int l15 = lane & 15, l4 = lane >> 4;
  const int rh = w >> 2, th = w & 3;     // wave sub-tile: 32r x 32t
  const int swz = (l15 & 7) << 4;

  const int bid = blockIdx.x;
  const int rs = bid & 7;
  const int tb = (bid >> 3) & 31;
  const int b  = bid >> 8;

  // ---- B fragments in registers: wave's 32 t x full K=256 i8 (32 VGPR) ----
  i32x4 bfr[2][4];
  {
    const char* base = tgtb + ((size_t)(b * HW + tb * TT + th * 32)) * 256;
#pragma unroll
    for (int nt = 0; nt < 2; ++nt) {
      const char* rp = base + (size_t)((nt * 16 + l15) * 256);
#pragma unroll
      for (int ks = 0; ks < 4; ++ks)
        bfr[nt][ks] = *(const i32x4*)(rp + ((ks * 64 + l4 * 16) ^ swz));
    }
  }

  f32x4 pacc[2];
  pacc[0] = f32x4{0.f, 0.f, 0.f, 0.f};
  pacc[1] = f32x4{0.f, 0.f, 0.f, 0.f};

  const char* Asrc = refb + ((size_t)(b * RTOT + rs * RPB)) * 256;

  // precomputed A-read base pointers (buf0); buf1 reached via +16384 immediate
  const char* ap00 = &Ash[0][(rh * 32 +  0 + l15) * 256 + ((     l4 * 16) ^ swz)];
  const char* ap01 = &Ash[0][(rh * 32 +  0 + l15) * 256 + ((64 + l4 * 16) ^ swz)];
  const char* ap10 = &Ash[0][(rh * 32 + 16 + l15) * 256 + ((     l4 * 16) ^ swz)];
  const char* ap11 = &Ash[0][(rh * 32 + 16 + l15) * 256 + ((64 + l4 * 16) ^ swz)];

  // stage chunk at src -> dbuf (16 KB = 16 segs of 1 KB, 2 per wave)
  auto stage = [&](const char* s, char* dbuf) {
#pragma unroll
    for (int i2 = 0; i2 < 2; ++i2) {
      const int seg = i2 * 8 + w;
      async16(s + seg * 1024 + lane * 16, dbuf + seg * 1024);
    }
  };
  // QK^T of one chunk: 16 i8-MFMA/wave (K=64 each); int accumulate (exact)
  auto qk = [&](i32x4 (&acc)[2][2], const int OFS) {
#pragma unroll
    for (int i2 = 0; i2 < 2; ++i2)
#pragma unroll
      for (int j = 0; j < 2; ++j) acc[i2][j] = i32x4{0, 0, 0, 0};
    __builtin_amdgcn_s_setprio(1);
#pragma unroll
    for (int ks = 0; ks < 4; ++ks) {
      const int ko = OFS + (ks >> 1) * 128;
      const i32x4 af0 = *(const i32x4*)(((ks & 1) ? ap01 : ap00) + ko);
      const i32x4 af1 = *(const i32x4*)(((ks & 1) ? ap11 : ap10) + ko);
#pragma unroll
      for (int nt = 0; nt < 2; ++nt)
        acc[0][nt] = __builtin_amdgcn_mfma_i32_16x16x64_i8(
            af0, bfr[nt][ks], acc[0][nt], 0, 0, 0);
#pragma unroll
      for (int nt = 0; nt < 2; ++nt)
        acc[1][nt] = __builtin_amdgcn_mfma_i32_16x16x64_i8(
            af1, bfr[nt][ks], acc[1][nt], 0, 0, 0);
    }
    __builtin_amdgcn_s_setprio(0);
  };
  // dequant+exp2+pack+PV (wave-local; C/D reg layout IS the PV B-frag layout)
  auto pv = [&](const i32x4 (&acc)[2][2], unsigned la, unsigned lb2) {
    union { bf16x8 v; unsigned u[4]; } lf;
    lf.u[0] = oh2(la, l15);        lf.u[1] = oh2(la >> 16, l15);
    lf.u[2] = oh2(lb2, l15);       lf.u[3] = oh2(lb2 >> 16, l15);
#pragma unroll
    for (int nt = 0; nt < 2; ++nt) {
      const i32x4 a0 = acc[0][nt], a1 = acc[1][nt];
      float p0 = __builtin_amdgcn_exp2f(__builtin_fmaf((float)a0[0], SC2, C0f));
      float p1 = __builtin_amdgcn_exp2f(__builtin_fmaf((float)a0[1], SC2, C0f));
      float p2 = __builtin_amdgcn_exp2f(__builtin_fmaf((float)a0[2], SC2, C0f));
      float p3 = __builtin_amdgcn_exp2f(__builtin_fmaf((float)a0[3], SC2, C0f));
      float p4 = __builtin_amdgcn_exp2f(__builtin_fmaf((float)a1[0], SC2, C0f));
      float p5 = __builtin_amdgcn_exp2f(__builtin_fmaf((float)a1[1], SC2, C0f));
      float p6 = __builtin_amdgcn_exp2f(__builtin_fmaf((float)a1[2], SC2, C0f));
      float p7 = __builtin_amdgcn_exp2f(__builtin_fmaf((float)a1[3], SC2, C0f));
      union { bf16x8 v; unsigned u[4]; } pf;
      pf.u[0] = cvtpk(p0, p1); pf.u[1] = cvtpk(p2, p3);
      pf.u[2] = cvtpk(p4, p5); pf.u[3] = cvtpk(p6, p7);
      pacc[nt] = __builtin_amdgcn_mfma_f32_16x16x32_bf16(lf.v, pf.v, pacc[nt], 0, 0, 0);
    }
  };

  i32x4 accE[2][2], accO[2][2];   // even-chunk / odd-chunk acc sets (both live on odd path)
  const unsigned char* lbp = lab8 + b * RTOT + rs * RPB + rh * 32 + l4 * 4;
  const char* Acur = Asrc + 2 * (RR * 256);   // global source of chunk 2
  const bool mfmaFirst = (w & 1) != 0;

  // prologue: labels(0); stage(0)->buf0; drain; stage(1)->buf1; qk(0)->accE
  unsigned la_p = *(const unsigned*)lbp;
  unsigned lb_p = *(const unsigned*)(lbp + 16);
  lbp += RR;
  stage(Asrc, &Ash[0][0]);
  __syncthreads();
  stage(Asrc + RR * 256, &Ash[1][0]);
  qk(accE, 0);

#pragma unroll 1
  for (int i = 0; i < 11; ++i) {
    {   // step: chunk c=1+2i (odd, buf1) -> accO; prev = accE
      __syncthreads();                   // all pending vmem >= 1 chunk old
      const unsigned la_n = *(const unsigned*)lbp;
      const unsigned lb_n = *(const unsigned*)(lbp + 16);
      lbp += RR;
      stage(Acur, &Ash[0][0]); Acur += RR * 256;
      if (mfmaFirst) { qk(accO, 16384); pv(accE, la_p, lb_p); }
      else           { pv(accE, la_p, lb_p); qk(accO, 16384); }
      la_p = la_n; lb_p = lb_n;
    }
    {   // step: chunk c=2+2i (even, buf0) -> accE; prev = accO
      __syncthreads();
      const unsigned la_n = *(const unsigned*)lbp;
      const unsigned lb_n = *(const unsigned*)(lbp + 16);
      lbp += RR;
      stage(Acur, &Ash[1][0]); Acur += RR * 256;
      if (mfmaFirst) { qk(accE, 0); pv(accO, la_p, lb_p); }
      else           { pv(accO, la_p, lb_p); qk(accE, 0); }
      la_p = la_n; lb_p = lb_n;
    }
  }
  {   // chunk 23 (odd, buf1) -> accO: no stage; then final pv(accO)
    __syncthreads();                     // drain DMA(23) (1 chunk old)
    const unsigned la_n = *(const unsigned*)lbp;   // labels(23)
    const unsigned lb_n = *(const unsigned*)(lbp + 16);
    if (mfmaFirst) { qk(accO, 16384); pv(accE, la_p, lb_p); }
    else           { pv(accE, la_p, lb_p); qk(accO, 16384); }
    pv(accO, la_n, lb_n);                // chunk 23
  }

  // ---- cross-wave reduction of rh pairs (once), then global write ----
  __syncthreads();                       // everyone done with Ash (no DMA pending)
  float* sc = (float*)&Ash[0][0];        // 8 KB scratch
  if (rh == 1) {
#pragma unroll
    for (int nt = 0; nt < 2; ++nt)
      *(f32x4*)&sc[((th * 64 + lane) * 2 + nt) * 4] = pacc[nt];
  }
  __syncthreads();
  if (rh == 0) {
#pragma unroll
    for (int nt = 0; nt < 2; ++nt) {
      pacc[nt] += *(const f32x4*)&sc[((th * 64 + lane) * 2 + nt) * 4];
      const int t = tb * TT + th * 32 + nt * 16 + l15;
      const size_t o = (((size_t)(rs * B_ + b)) * HW + t) * 16 + l4 * 4;
      *(f32x4*)&pred[o] = pacc[nt];
    }
  }
}

// ---------------- kernel 3: per-pixel loss terms + block reduce ----------------
__global__ __launch_bounds__(256) void k_epi(const float* __restrict__ pred,
                                             const int* __restrict__ tl,
                                             float* __restrict__ red) {
  const int idx = blockIdx.x * 256 + threadIdx.x;   // < 8192
  const int b = idx >> 12, t = idx & 4095;
  union { f32x4 v[3]; float f[12]; } S;
  S.v[0] = f32x4{0.f, 0.f, 0.f, 0.f};
  S.v[1] = f32x4{0.f, 0.f, 0.f, 0.f};
  S.v[2] = f32x4{0.f, 0.f, 0.f, 0.f};
#pragma unroll
  for (int r = 0; r < RS; ++r) {
    const f32x4* p = (const f32x4*)&pred[(((size_t)(r * B_ + b)) * HW + t) * 16];
    S.v[0] += p[0]; S.v[1] += p[1]; S.v[2] += p[2];
  }
  float T = 0.f;
#pragma unroll
  for (int d = 0; d < DCLS; ++d) T += S.f[d];
  const float inv = 1.f / T;
  const int lb = tl[idx];
  float se = 0.f, zt = 0.f;
#pragma unroll
  for (int d = 0; d < DCLS; ++d) {
    const float z = S.f[d] * inv;      // pred prob in [0,1]
    se += __expf(z);
    if (d == lb) zt = z;
  }
  const float logpt = zt - __logf(se);
  const float pt = __expf(zt) / se;
  const float focal = sqrtf(fmaxf(1.f - pt, 0.f));   // gamma = 0.5

  float lp = logpt, fo = focal;
#pragma unroll
  for (int off = 32; off; off >>= 1) {
    lp += __shfl_down(lp, off);
    fo += __shfl_down(fo, off);
  }
  __shared__ float rb_[8];
  const int lane = threadIdx.x & 63, wv = threadIdx.x >> 6;
  if (lane == 0) { rb_[wv] = lp; rb_[4 + wv] = fo; }
  __syncthreads();
  if (threadIdx.x == 0) {
    red[blockIdx.x * 2 + 0] = rb_[0] + rb_[1] + rb_[2] + rb_[3];
    red[blockIdx.x * 2 + 1] = rb_[4] + rb_[5] + rb_[6] + rb_[7];
  }
}

// ---------------- kernel 4: final scalar ----------------
__global__ void k_fin(const float* __restrict__ red, float* __restrict__ out) {
  const int tid = threadIdx.x;   // 64
  float lp = 0.f, fo = 0.f;
  if (tid < 32) { lp = red[tid * 2]; fo = red[tid * 2 + 1]; }
#pragma unroll
  for (int off = 16; off; off >>= 1) {
    lp += __shfl_down(lp, off);
    fo += __shfl_down(fo, off);
  }
  if (tid == 0) {
    const float ce = -lp / (float)NPIX;       // ce = -mean(log_pt)
    out[0] = ce * (fo / (float)NPIX);         // loss = ce * mean(focal)
  }
}

extern "C" void kernel_launch(void* const* d_in, const int* in_sizes, int n_in,
                              void* d_out, int out_size, void* d_ws, size_t ws_size,
                              hipStream_t stream)
{
  const float* ref  = (const float*)d_in[0];
  const float* tgt  = (const float*)d_in[1];
  const float* rl   = (const float*)d_in[2];
  const int*   tlab = (const int*)d_in[3];
  float* out = (float*)d_out;

  char* ws = (char*)d_ws;
  char* refb = ws;                                    // 32768 rows * 256 B = 8 MB (ref + tgt)
  char* tgtb = ws + (size_t)24576 * 256;              // tgt rows start at 24576
  unsigned char* lab8 = (unsigned char*)(ws + 8388608);           // 24 KB (pad 32 KB)
  float* pred = (float*)(ws + 8388608 + 32768);                   // 4 MB (RS*B*HW*16 f32)
  float* red  = (float*)(ws + 8388608 + 32768 + 4194304);         // 256 B

  k_pre<<<1120, 256, 0, stream>>>(ref, tgt, rl, refb, lab8);
  k_main<<<512, 512, 0, stream>>>(refb, tgtb, lab8, pred);
  k_epi<<<32, 256, 0, stream>>>(pred, tlab, red);
  k_fin<<<1, 64, 0, stream>>>(red, out);
}